// Round 4
// baseline (205.827 us; speedup 1.0000x reference)
//
#include <hip/hip_runtime.h>

typedef unsigned short u16;
typedef unsigned int   u32;
typedef __attribute__((ext_vector_type(4))) float f32x4;
typedef __attribute__((ext_vector_type(8))) short bf16x8;
typedef __attribute__((ext_vector_type(8))) unsigned short u16x8;
typedef __attribute__((ext_vector_type(4))) unsigned short u16x4;

#define MROWS 4096
#define DDIM  1024

__device__ __forceinline__ u16 f2bf(float f) {
  u32 u = __float_as_uint(f);
  return (u16)((u + 0x7FFFu + ((u >> 16) & 1u)) >> 16);   // RNE
}
__device__ __forceinline__ float bf2f(u16 h) { return __uint_as_float(((u32)h) << 16); }

// ---------- JAX partitionable threefry2x32, key(42): bits(n) = o0^o1 ----------
__device__ __forceinline__ u32 rotl32(u32 x, int r) { return (x << r) | (x >> (32 - r)); }
__device__ __forceinline__ u32 threefry_bits(u32 n) {
  const u32 K0 = 0u, K1 = 42u, K2 = 0x1BD11BDAu ^ 0u ^ 42u;
  u32 x0 = K0;
  u32 x1 = n + K1;
#define TF4(a,b,c,d) \
  x0 += x1; x1 = rotl32(x1, a); x1 ^= x0; \
  x0 += x1; x1 = rotl32(x1, b); x1 ^= x0; \
  x0 += x1; x1 = rotl32(x1, c); x1 ^= x0; \
  x0 += x1; x1 = rotl32(x1, d); x1 ^= x0;
  TF4(13,15,26,6);  x0 += K1; x1 += K2 + 1u;
  TF4(17,29,16,24); x0 += K2; x1 += K0 + 2u;
  TF4(13,15,26,6);  x0 += K0; x1 += K1 + 3u;
  TF4(17,29,16,24); x0 += K1; x1 += K2 + 4u;
  TF4(13,15,26,6);  x0 += K2; x1 += K0 + 5u;
#undef TF4
  return x0 ^ x1;
}

// ============ expand: 3-term hi/lo split ============
// element e -> slots [3e..3e+2]: A-pattern [ah,ah,al], B-pattern [bh,bl,bh]
__global__ __launch_bounds__(256)
void expand3(const float4* __restrict__ x, u16* __restrict__ out, float scale, int patA) {
  int t = blockIdx.x * 256 + threadIdx.x;      // 524288 threads, 8 floats each
  float4 v0 = x[(size_t)t * 2], v1 = x[(size_t)t * 2 + 1];
  float vv[8] = {v0.x*scale, v0.y*scale, v0.z*scale, v0.w*scale,
                 v1.x*scale, v1.y*scale, v1.z*scale, v1.w*scale};
  u16 o[24];
#pragma unroll
  for (int j = 0; j < 8; ++j) {
    u16 h = f2bf(vv[j]);
    u16 l = f2bf(vv[j] - bf2f(h));             // Sterbenz-exact residual, RNE
    if (patA) { o[3*j]=h; o[3*j+1]=h; o[3*j+2]=l; }
    else      { o[3*j]=h; o[3*j+1]=l; o[3*j+2]=h; }
  }
  u16x8* dst = (u16x8*)(out + (size_t)t * 24);
#pragma unroll
  for (int q = 0; q < 3; ++q) {
    u16x8 wv;
#pragma unroll
    for (int j = 0; j < 8; ++j) wv[j] = o[q*8+j];
    dst[q] = wv;
  }
}

// ============ V transpose to bf16: VT[d][k] = bf16(x2[k][d]) ============
__global__ __launch_bounds__(256)
void transpose_bf16(const float* __restrict__ x2, u16* __restrict__ VT) {
  __shared__ float tile[64][65];
  int tid = threadIdx.x;
  int dt = blockIdx.x;   // 16 D-tiles
  int kt = blockIdx.y;   // 64 K-tiles
#pragma unroll
  for (int it = 0; it < 16; ++it) {
    int lin = it * 256 + tid;
    int r = lin >> 6, c = lin & 63;
    tile[r][c] = x2[(size_t)(kt*64 + r) * DDIM + dt*64 + c];
  }
  __syncthreads();
#pragma unroll
  for (int it = 0; it < 16; ++it) {
    int lin = it * 256 + tid;
    int dr = lin >> 6, kc = lin & 63;
    VT[(size_t)(dt*64 + dr) * MROWS + kt*64 + kc] = f2bf(tile[kc][dr]);
  }
}

// ============ 256x256 8-phase GEMM (round-2 schedule) + fused mask-gen ============
// 512 thr (8 waves 2Mx4N), BK=64, dbuf LDS 128KB, chunk-XOR swizzle,
// even 2-load/phase staging, counted vmcnt(6) at p4/p8, setprio on MFMA.
// DOMASK: one threefry call per phase (p1..p6), post-barrier (fills lgkm-wait
// stall; VALU co-issues with other waves' MFMA). No in-loop stores.
__device__ __forceinline__ void gload16(const u16* g, u16* l) {
  __builtin_amdgcn_global_load_lds(
      (const __attribute__((address_space(1))) void*)g,
      (__attribute__((address_space(3))) void*)l, 16, 0, 0);
}

#define BARRIER() do { asm volatile("" ::: "memory"); __builtin_amdgcn_s_barrier(); \
                       asm volatile("" ::: "memory"); } while (0)
#define LGKM0()   do { asm volatile("s_waitcnt lgkmcnt(0)" ::: "memory"); \
                       __builtin_amdgcn_sched_barrier(0); } while (0)
#define VMCNT6()  do { asm volatile("s_waitcnt vmcnt(6)" ::: "memory"); } while (0)

__device__ __forceinline__ void read_a4(bf16x8 (&aF)[4][2], const u16* base, const int (&off)[4][2]) {
#pragma unroll
  for (int m = 0; m < 4; ++m)
#pragma unroll
    for (int kx = 0; kx < 2; ++kx)
      aF[m][kx] = *(const bf16x8*)(base + off[m][kx]);
}
__device__ __forceinline__ void read_b2(bf16x8 (&bF)[2][2], const u16* base, const int (&off)[2][2]) {
#pragma unroll
  for (int n = 0; n < 2; ++n)
#pragma unroll
    for (int kx = 0; kx < 2; ++kx)
      bF[n][kx] = *(const bf16x8*)(base + off[n][kx]);
}
__device__ __forceinline__ void mma_quad(f32x4 (&acc)[8][4], const bf16x8 (&aF)[4][2],
                                         const bf16x8 (&bF)[2][2], int MH, int NH) {
#pragma unroll
  for (int kx = 0; kx < 2; ++kx)
#pragma unroll
    for (int m = 0; m < 4; ++m)
#pragma unroll
      for (int n = 0; n < 2; ++n)
        acc[MH*4+m][NH*2+n] = __builtin_amdgcn_mfma_f32_16x16x32_bf16(
            aF[m][kx], bF[n][kx], acc[MH*4+m][NH*2+n], 0, 0, 0);
}

// LDS u16 layout: A(d,h) = (d*2+h)*8192 ; B(d,h) = 32768 + (d*2+h)*8192
template <bool DOMASK>
__global__ __launch_bounds__(512, 2)
void gemm256(const u16* __restrict__ A, const u16* __restrict__ Bt, float* __restrict__ C,
             int M, int N, int K, int ntpc, u32* __restrict__ mask) {
  __shared__ u16 smem[65536];   // 128 KiB
  const int tid = threadIdx.x;
  const int lane = tid & 63;
  const int w = tid >> 6;
  const int wr = w >> 2;          // 0..1
  const int wc = w & 3;           // 0..3
  const int fr = lane & 15;
  const int hi = lane >> 4;

  const long bm = (long)blockIdx.y * 256;
  const long bn = (long)blockIdx.x * 256;
  const size_t kcol0 = (size_t)blockIdx.z * ntpc * 64;
  float* Cz = C + (size_t)blockIdx.z * (size_t)M * N;

  // staging: thread -> (row=tid>>3, chunk=tid&7); global src chunk pre-swizzled
  const int srow = tid >> 3;
  const int scol = (((tid & 7) ^ (srow & 7)) << 3);
  const u16* Abase = A  + (size_t)(bm + srow) * K + kcol0 + scol;
  const u16* Bbase = Bt + (size_t)(bn + srow) * K + kcol0 + scol;

  // per-lane swizzled read offsets (u16 units within a half-tile [128][64])
  int offA[4][2], offB[2][2];
#pragma unroll
  for (int m = 0; m < 4; ++m)
#pragma unroll
    for (int kx = 0; kx < 2; ++kx) {
      int r = m*32 + wr*16 + fr;
      int c0 = kx*4 + hi;
      offA[m][kx] = r*64 + (((c0 ^ (r & 7))) << 3);
    }
#pragma unroll
  for (int n = 0; n < 2; ++n)
#pragma unroll
    for (int kx = 0; kx < 2; ++kx) {
      int r = n*64 + wc*16 + fr;
      int c0 = kx*4 + hi;
      offB[n][kx] = r*64 + (((c0 ^ (r & 7))) << 3);
    }

  f32x4 acc[8][4];
#pragma unroll
  for (int m = 0; m < 8; ++m)
#pragma unroll
    for (int n = 0; n < 4; ++n) acc[m][n] = (f32x4){0.f, 0.f, 0.f, 0.f};
  bf16x8 aF[4][2], b0F[2][2], b1F[2][2];

  // mask accumulators: 4 named words (static access only, rule #20)
  u32 mw0 = 0, mw1 = 0, mw2 = 0, mw3 = 0;
  u32 ci = 0;
#define MASK_STEP() do { if (DOMASK) { if (ci < 128u) { \
    u32 lw  = (u32)tid * 4u + (ci >> 5); \
    u32 n   = (((u32)bm + (lw >> 3)) << 12) + (u32)bn + ((lw & 7u) << 5) + (ci & 31u); \
    u32 bit = (threefry_bits(n) >> 31) << (ci & 31u); \
    u32 sel = ci >> 5; \
    mw0 |= (sel == 0u) ? bit : 0u; \
    mw1 |= (sel == 1u) ? bit : 0u; \
    mw2 |= (sel == 2u) ? bit : 0u; \
    mw3 |= (sel == 3u) ? bit : 0u; \
    ++ci; } } } while (0)

#define STAGE_A(TAU,H,D) do { \
    const u16* _s = Abase + (size_t)(H)*128*K + (size_t)(TAU)*64; \
    u16* _d = smem + ((D)*2+(H))*8192 + tid*8; \
    gload16(_s, _d); gload16(_s + (size_t)64*K, _d + 4096); } while (0)
#define STAGE_B(TAU,H,D) do { \
    const u16* _s = Bbase + (size_t)(H)*128*K + (size_t)(TAU)*64; \
    u16* _d = smem + 32768 + ((D)*2+(H))*8192 + tid*8; \
    gload16(_s, _d); gload16(_s + (size_t)64*K, _d + 4096); } while (0)

  // prologue: tile0 (4 halves, oldest 8 loads) + tile1 A0,B0,B1 (6 loads)
  STAGE_A(0,0,0); STAGE_B(0,0,0); STAGE_B(0,1,0); STAGE_A(0,1,0);
  STAGE_A(1,0,1); STAGE_B(1,0,1); STAGE_B(1,1,1);
  VMCNT6();                 // tile0 fully landed
  BARRIER();

  const int nt = ntpc;
  for (int T = 0; T < nt; T += 2) {
    const int t1 = T + 1;
    const int t2 = (T + 2 < nt) ? T + 2 : nt - 1;   // tail: dummy re-stage (regions dead)
    const int t3 = (T + 3 < nt) ? T + 3 : nt - 1;

    // p1: quad(0,0) tile T (buf0)
    read_a4(aF, smem + 0, offA);            // A0 b0
    read_b2(b0F, smem + 32768, offB);       // B0 b0
    STAGE_A(t1, 1, 1);                      // A1(T+1)
    BARRIER(); MASK_STEP(); LGKM0();
    __builtin_amdgcn_s_setprio(1); mma_quad(acc, aF, b0F, 0, 0); __builtin_amdgcn_s_setprio(0);
    BARRIER();
    // p2: quad(0,1)
    read_b2(b1F, smem + 40960, offB);       // B1 b0
    STAGE_A(t2, 0, 0);                      // A0(T+2)
    BARRIER(); MASK_STEP(); LGKM0();
    __builtin_amdgcn_s_setprio(1); mma_quad(acc, aF, b1F, 0, 1); __builtin_amdgcn_s_setprio(0);
    BARRIER();
    // p3: quad(1,0)
    read_a4(aF, smem + 8192, offA);         // A1 b0
    STAGE_B(t2, 0, 0);                      // B0(T+2)
    BARRIER(); MASK_STEP(); LGKM0();
    __builtin_amdgcn_s_setprio(1); mma_quad(acc, aF, b0F, 1, 0); __builtin_amdgcn_s_setprio(0);
    BARRIER();
    // p4: quad(1,1)  [vmcnt(6): tile T+1 fully landed before p5]
    STAGE_B(t2, 1, 0);                      // B1(T+2)
    VMCNT6();
    BARRIER(); MASK_STEP(); LGKM0();
    __builtin_amdgcn_s_setprio(1); mma_quad(acc, aF, b1F, 1, 1); __builtin_amdgcn_s_setprio(0);
    BARRIER();
    // p5: quad(0,0) tile T+1 (buf1)
    read_a4(aF, smem + 16384, offA);        // A0 b1
    read_b2(b0F, smem + 49152, offB);       // B0 b1
    STAGE_A(t2, 1, 0);                      // A1(T+2)
    BARRIER(); MASK_STEP(); LGKM0();
    __builtin_amdgcn_s_setprio(1); mma_quad(acc, aF, b0F, 0, 0); __builtin_amdgcn_s_setprio(0);
    BARRIER();
    // p6: quad(0,1)
    read_b2(b1F, smem + 57344, offB);       // B1 b1
    STAGE_A(t3, 0, 1);                      // A0(T+3)
    BARRIER(); MASK_STEP(); LGKM0();
    __builtin_amdgcn_s_setprio(1); mma_quad(acc, aF, b1F, 0, 1); __builtin_amdgcn_s_setprio(0);
    BARRIER();
    // p7: quad(1,0)
    read_a4(aF, smem + 24576, offA);        // A1 b1
    STAGE_B(t3, 0, 1);                      // B0(T+3)
    BARRIER(); LGKM0();
    __builtin_amdgcn_s_setprio(1); mma_quad(acc, aF, b0F, 1, 0); __builtin_amdgcn_s_setprio(0);
    BARRIER();
    // p8: quad(1,1)  [vmcnt(6): tile T+2 fully landed before p1']
    STAGE_B(t3, 1, 1);                      // B1(T+3)
    VMCNT6();
    BARRIER(); LGKM0();
    __builtin_amdgcn_s_setprio(1); mma_quad(acc, aF, b1F, 1, 1); __builtin_amdgcn_s_setprio(0);
    BARRIER();
  }
#undef STAGE_A
#undef STAGE_B
#undef MASK_STEP

  // mask write: thread owns local words tid*4..tid*4+3 of this 256x256 tile
  if (DOMASK) {
#pragma unroll
    for (int j = 0; j < 4; ++j) {
      u32 lw = (u32)tid * 4u + (u32)j;
      u32 idx = ((u32)bm + (lw >> 3)) * 128u + ((u32)bn >> 5) + (lw & 7u);
      u32 val = (j == 0) ? mw0 : (j == 1) ? mw1 : (j == 2) ? mw2 : mw3;
      mask[idx] = val;
    }
  }

  // epilogue: C/D layout col=lane&15, row=(lane>>4)*4+reg  [verified m89/m91]
#pragma unroll
  for (int m = 0; m < 8; ++m)
#pragma unroll
    for (int n = 0; n < 4; ++n) {
      size_t row0 = (size_t)(bm + m*32 + wr*16 + hi*4);
      size_t col  = (size_t)(bn + n*64 + wc*16 + fr);
#pragma unroll
      for (int r = 0; r < 4; ++r)
        Cz[(row0 + r) * N + col] = acc[m][n][r];
    }
}

// ============ softmax + precomputed dropout mask -> bf16 P ============
__global__ __launch_bounds__(256)
void softmax_dropout(const float* __restrict__ S, const u32* __restrict__ mask,
                     u16* __restrict__ P) {
  const int tid  = threadIdx.x;
  const int lane = tid & 63;
  const int w    = tid >> 6;
  const int row  = blockIdx.x * 4 + w;   // one row per wave
  const float4* Sr = (const float4*)(S + (size_t)row * MROWS);
  float4 v[16];
#pragma unroll
  for (int i = 0; i < 16; ++i) v[i] = Sr[i * 64 + lane];
  float m = -3.0e38f;
#pragma unroll
  for (int i = 0; i < 16; ++i)
    m = fmaxf(m, fmaxf(fmaxf(v[i].x, v[i].y), fmaxf(v[i].z, v[i].w)));
#pragma unroll
  for (int off = 32; off > 0; off >>= 1) m = fmaxf(m, __shfl_xor(m, off, 64));
  float s = 0.0f;
#pragma unroll
  for (int i = 0; i < 16; ++i) {
    v[i].x = __expf(v[i].x - m); v[i].y = __expf(v[i].y - m);
    v[i].z = __expf(v[i].z - m); v[i].w = __expf(v[i].w - m);
    s += v[i].x + v[i].y + v[i].z + v[i].w;
  }
#pragma unroll
  for (int off = 32; off > 0; off >>= 1) s += __shfl_xor(s, off, 64);
  const float inv = 2.0f / s;            // softmax normalize * 1/(1-p)
  u16* Pr = P + (size_t)row * MROWS;
  const u32* Mw = mask + (size_t)row * 128;
#pragma unroll
  for (int i = 0; i < 16; ++i) {
    int j0 = (i * 64 + lane) * 4;
    u32 word = Mw[j0 >> 5];
    int sh = j0 & 31;
    float e[4] = {v[i].x, v[i].y, v[i].z, v[i].w};
    u16x4 o;
#pragma unroll
    for (int c = 0; c < 4; ++c) {
      float val = ((word >> (sh + c)) & 1u) ? 0.0f : e[c] * inv;
      o[c] = f2bf(val);
    }
    *(u16x4*)(Pr + j0) = o;
  }
}

// ============ split-K reduction: out = sum of 4 partials ============
__global__ __launch_bounds__(256)
void reduce4(const float4* __restrict__ p, float4* __restrict__ out) {
  size_t i = (size_t)blockIdx.x * 256 + threadIdx.x;
  const size_t NP = (size_t)MROWS * DDIM / 4;
  float4 a = p[i], b = p[i + NP], c = p[i + 2*NP], d = p[i + 3*NP];
  float4 r;
  r.x = a.x + b.x + c.x + d.x;
  r.y = a.y + b.y + c.y + d.y;
  r.z = a.z + b.z + c.z + d.z;
  r.w = a.w + b.w + c.w + d.w;
  out[i] = r;
}

// ============ launch ============
extern "C" void kernel_launch(void* const* d_in, const int* in_sizes, int n_in,
                              void* d_out, int out_size, void* d_ws, size_t ws_size,
                              hipStream_t stream) {
  const float* x1 = (const float*)d_in[0];
  const float* x2 = (const float*)d_in[1];
  float* out = (float*)d_out;
  char* ws = (char*)d_ws;

  // ws layout (bytes):
  //   XA [0,24M) | XB [24M,48M) | VT [48M,56M) | S [56M,120M) | MASK [120M,122M)
  //   P (32M) overlays XA+XB after GEMM1 ; partials (64M) overlay S after softmax
  const size_t OFF_XB   = 25165824;
  const size_t OFF_VT   = 50331648;
  const size_t OFF_S    = 58720256;
  const size_t OFF_MASK = 125829120;
  const size_t NEED     = 127926272;
  if (ws_size < NEED) {
    hipMemsetAsync(d_out, 0x7F, (size_t)out_size * sizeof(float), stream);
    return;
  }
  u16*   XA = (u16*)(ws);
  u16*   XB = (u16*)(ws + OFF_XB);
  u16*   VT = (u16*)(ws + OFF_VT);
  float* S  = (float*)(ws + OFF_S);
  float* PT = (float*)(ws + OFF_S);     // partials reuse S
  u32*   MK = (u32*)(ws + OFF_MASK);
  u16*   P  = (u16*)(ws);               // reuses XA(+XB) region

  expand3<<<2048, 256, 0, stream>>>((const float4*)x1, XA, 4.0f, 1);  // scale folded into x1
  expand3<<<2048, 256, 0, stream>>>((const float4*)x2, XB, 1.0f, 0);
  transpose_bf16<<<dim3(16, 64), 256, 0, stream>>>(x2, VT);
  // S = (4*x1) @ x2^T via 3-term expanded K = 3072 ; mask-gen fused into stalls
  gemm256<true><<<dim3(16, 16, 1), 512, 0, stream>>>(XA, XB, S, 4096, 4096, 3072, 48, MK);
  softmax_dropout<<<1024, 256, 0, stream>>>(S, MK, P);
  // O = P @ V: split-K x4 (K=4096, 16 tiles/chunk), then reduce
  gemm256<false><<<dim3(4, 16, 4), 512, 0, stream>>>(P, VT, PT, 4096, 1024, 4096, 16, nullptr);
  reduce4<<<4096, 256, 0, stream>>>((const float4*)PT, (float4*)out);
}

// Round 5
// 192.021 us; speedup vs baseline: 1.0719x; 1.0719x over previous
//
#include <hip/hip_runtime.h>

typedef unsigned short u16;
typedef unsigned int   u32;
typedef __attribute__((ext_vector_type(4))) float f32x4;
typedef __attribute__((ext_vector_type(8))) short bf16x8;
typedef __attribute__((ext_vector_type(8))) unsigned short u16x8;
typedef __attribute__((ext_vector_type(4))) unsigned short u16x4;

#define MROWS 4096
#define DDIM  1024

__device__ __forceinline__ u16 f2bf(float f) {
  u32 u = __float_as_uint(f);
  return (u16)((u + 0x7FFFu + ((u >> 16) & 1u)) >> 16);   // RNE
}
__device__ __forceinline__ float bf2f(u16 h) { return __uint_as_float(((u32)h) << 16); }

// ---------- JAX partitionable threefry2x32, key(42): bits(n) = o0^o1 ----------
__device__ __forceinline__ u32 rotl32(u32 x, int r) { return (x << r) | (x >> (32 - r)); }
__device__ __forceinline__ u32 threefry_bits(u32 n) {
  const u32 K0 = 0u, K1 = 42u, K2 = 0x1BD11BDAu ^ 0u ^ 42u;
  u32 x0 = K0;
  u32 x1 = n + K1;
#define TF4(a,b,c,d) \
  x0 += x1; x1 = rotl32(x1, a); x1 ^= x0; \
  x0 += x1; x1 = rotl32(x1, b); x1 ^= x0; \
  x0 += x1; x1 = rotl32(x1, c); x1 ^= x0; \
  x0 += x1; x1 = rotl32(x1, d); x1 ^= x0;
  TF4(13,15,26,6);  x0 += K1; x1 += K2 + 1u;
  TF4(17,29,16,24); x0 += K2; x1 += K0 + 2u;
  TF4(13,15,26,6);  x0 += K0; x1 += K1 + 3u;
  TF4(17,29,16,24); x0 += K1; x1 += K2 + 4u;
  TF4(13,15,26,6);  x0 += K2; x1 += K0 + 5u;
#undef TF4
  return x0 ^ x1;
}

// ============ expand: 3-term hi/lo split + balanced mask-gen (16 calls/thread) ============
// element e -> slots [3e..3e+2]: A-pattern [ah,ah,al], B-pattern [bh,bl,bh]
__global__ __launch_bounds__(256)
void expand3(const float4* __restrict__ x, u16* __restrict__ out, float scale, int patA,
             u32* __restrict__ mask, u32 wordBase) {
  int t = blockIdx.x * 256 + threadIdx.x;      // 524288 threads, 8 floats each
  float4 v0 = x[(size_t)t * 2], v1 = x[(size_t)t * 2 + 1];
  float vv[8] = {v0.x*scale, v0.y*scale, v0.z*scale, v0.w*scale,
                 v1.x*scale, v1.y*scale, v1.z*scale, v1.w*scale};
  u16 o[24];
#pragma unroll
  for (int j = 0; j < 8; ++j) {
    u16 h = f2bf(vv[j]);
    u16 l = f2bf(vv[j] - bf2f(h));             // Sterbenz-exact residual, RNE
    if (patA) { o[3*j]=h; o[3*j+1]=h; o[3*j+2]=l; }
    else      { o[3*j]=h; o[3*j+1]=l; o[3*j+2]=h; }
  }
  u16x8* dst = (u16x8*)(out + (size_t)t * 24);
#pragma unroll
  for (int q = 0; q < 3; ++q) {
    u16x8 wv;
#pragma unroll
    for (int j = 0; j < 8; ++j) wv[j] = o[q*8+j];
    dst[q] = wv;
  }
  // mask: pair of threads builds one 32-bit word (16 threefry calls each)
  u32 w = wordBase + ((u32)t >> 1);
  u32 sh = ((u32)t & 1u) << 4;                 // 0 or 16
  u32 n0 = w * 32u + sh;
  u32 half = 0;
#pragma unroll 4
  for (int b = 0; b < 16; ++b) half |= (threefry_bits(n0 + (u32)b) >> 31) << (sh + b);
  u32 word = half | (u32)__shfl_xor((int)half, 1, 64);
  if ((t & 1) == 0) mask[w] = word;
}

// ============ V transpose to bf16: VT[d][k] = bf16(x2[k][d]) ============
__global__ __launch_bounds__(256)
void transpose_bf16(const float* __restrict__ x2, u16* __restrict__ VT) {
  __shared__ float tile[64][65];
  int tid = threadIdx.x;
  int dt = blockIdx.x;   // 16 D-tiles
  int kt = blockIdx.y;   // 64 K-tiles
#pragma unroll
  for (int it = 0; it < 16; ++it) {
    int lin = it * 256 + tid;
    int r = lin >> 6, c = lin & 63;
    tile[r][c] = x2[(size_t)(kt*64 + r) * DDIM + dt*64 + c];
  }
  __syncthreads();
#pragma unroll
  for (int it = 0; it < 16; ++it) {
    int lin = it * 256 + tid;
    int dr = lin >> 6, kc = lin & 63;
    VT[(size_t)(dt*64 + dr) * MROWS + kt*64 + kc] = f2bf(tile[kc][dr]);
  }
}

// ============ 256x256 pipelined 8-phase GEMM: C[M,N] = A[M,K] * Bt[N,K]^T ============
// One-phase-ahead register pipeline: ds_reads in phase k feed MFMA of phase k+1.
// ONE barrier per phase; counted vmcnt (8/10) before barriers; compiler emits
// counted lgkmcnt before each MFMA automatically (C++ LDS loads, no asm reads).
__device__ __forceinline__ void gload16(const u16* g, u16* l) {
  __builtin_amdgcn_global_load_lds(
      (const __attribute__((address_space(1))) void*)g,
      (__attribute__((address_space(3))) void*)l, 16, 0, 0);
}

#define BARRIER() do { asm volatile("" ::: "memory"); __builtin_amdgcn_s_barrier(); \
                       asm volatile("" ::: "memory"); } while (0)
#define VMCNT(N)  asm volatile("s_waitcnt vmcnt(" #N ")" ::: "memory")
#define PRIO1()   __builtin_amdgcn_s_setprio(1)
#define PRIO0()   __builtin_amdgcn_s_setprio(0)

__device__ __forceinline__ void mma_quad(f32x4 (&acc)[8][4], const bf16x8 (&aF)[4][2],
                                         const bf16x8 (&bF)[2][2], int MH, int NH) {
#pragma unroll
  for (int kx = 0; kx < 2; ++kx)
#pragma unroll
    for (int m = 0; m < 4; ++m)
#pragma unroll
      for (int n = 0; n < 2; ++n)
        acc[MH*4+m][NH*2+n] = __builtin_amdgcn_mfma_f32_16x16x32_bf16(
            aF[m][kx], bF[n][kx], acc[MH*4+m][NH*2+n], 0, 0, 0);
}

// LDS u16 layout: A(d,h) = (d*2+h)*8192 ; B(d,h) = 32768 + (d*2+h)*8192
template <bool OUT16>
__global__ __launch_bounds__(512, 2)
void gemm256(const u16* __restrict__ A, const u16* __restrict__ Bt, void* __restrict__ Cv,
             int M, int N, int K, int ntpc) {
  __shared__ u16 smem[65536];   // 128 KiB
  const int tid = threadIdx.x;
  const int lane = tid & 63;
  const int w = tid >> 6;
  const int wr = w >> 2;          // 0..1
  const int wc = w & 3;           // 0..3
  const int fr = lane & 15;
  const int hi = lane >> 4;

  const long bm = (long)blockIdx.y * 256;
  const long bn = (long)blockIdx.x * 256;
  const size_t kcol0 = (size_t)blockIdx.z * ntpc * 64;

  // staging: thread -> (row=tid>>3, chunk=tid&7); global src chunk pre-swizzled
  const int srow = tid >> 3;
  const int scol = (((tid & 7) ^ (srow & 7)) << 3);
  const u16* Abase = A  + (size_t)(bm + srow) * K + kcol0 + scol;
  const u16* Bbase = Bt + (size_t)(bn + srow) * K + kcol0 + scol;

  // swizzled read chunk offsets (u16 units); row ≡ fr (mod 8) for all frags
  const int csw0 = ((hi)     ^ (fr & 7)) << 3;
  const int csw1 = ((4 + hi) ^ (fr & 7)) << 3;
  const int arow = (wr*16 + fr) * 64;   // + m*2048 per m-frag
  const int brow = (wc*16 + fr) * 64;   // + n*4096 per n-frag

  // reads: RD_A -> 8 ds_read_b128, RD_B -> 4 (compile-time D,H fold to imm offsets)
#define RD_A(dst, D, H) do { \
    const u16* _b0 = smem + ((D)*2+(H))*8192 + arow + csw0; \
    const u16* _b1 = smem + ((D)*2+(H))*8192 + arow + csw1; \
    dst[0][0] = *(const bf16x8*)(_b0);        dst[0][1] = *(const bf16x8*)(_b1); \
    dst[1][0] = *(const bf16x8*)(_b0 + 2048); dst[1][1] = *(const bf16x8*)(_b1 + 2048); \
    dst[2][0] = *(const bf16x8*)(_b0 + 4096); dst[2][1] = *(const bf16x8*)(_b1 + 4096); \
    dst[3][0] = *(const bf16x8*)(_b0 + 6144); dst[3][1] = *(const bf16x8*)(_b1 + 6144); } while (0)
#define RD_B(dst, D, H) do { \
    const u16* _b0 = smem + 32768 + ((D)*2+(H))*8192 + brow + csw0; \
    const u16* _b1 = smem + 32768 + ((D)*2+(H))*8192 + brow + csw1; \
    dst[0][0] = *(const bf16x8*)(_b0);        dst[0][1] = *(const bf16x8*)(_b1); \
    dst[1][0] = *(const bf16x8*)(_b0 + 4096); dst[1][1] = *(const bf16x8*)(_b1 + 4096); } while (0)

  f32x4 acc[8][4];
#pragma unroll
  for (int m = 0; m < 8; ++m)
#pragma unroll
    for (int n = 0; n < 4; ++n) acc[m][n] = (f32x4){0.f, 0.f, 0.f, 0.f};
  bf16x8 a0[4][2], a1[4][2], b0[2][2], b1[2][2];

#define STAGE_A(TAU,H,D) do { \
    const u16* _s = Abase + (size_t)(H)*128*K + (size_t)(TAU)*64; \
    u16* _d = smem + ((D)*2+(H))*8192 + tid*8; \
    gload16(_s, _d); gload16(_s + (size_t)64*K, _d + 4096); } while (0)
#define STAGE_B(TAU,H,D) do { \
    const u16* _s = Bbase + (size_t)(H)*128*K + (size_t)(TAU)*64; \
    u16* _d = smem + 32768 + ((D)*2+(H))*8192 + tid*8; \
    gload16(_s, _d); gload16(_s + (size_t)64*K, _d + 4096); } while (0)

  // ---- prologue: prime LDS + register pipeline ----
  STAGE_A(0,0,0); STAGE_B(0,0,0);           // tile0 A0,B0 (4 loads)
  VMCNT(0); BARRIER();
  RD_A(a0, 0, 0); RD_B(b0, 0, 0);           // regs for MFMA p1 (12 lgkm outstanding)
  STAGE_B(0,1,0);                           // B1(0)   ["p3-slot"]
  STAGE_A(0,1,0);                           // A1(0)   ["p4-slot"]
  STAGE_A(1,0,1); STAGE_B(1,0,1);           // A0,B0(1)["p6-slot"]
  STAGE_B(1,1,1);                           // B1(1)   ["p7-slot"]
  STAGE_A(1,1,1);                           // A1(1)   ["p8-slot"]
  VMCNT(10); BARRIER();                     // drains B1(0); 10 loads in flight

  const int nt = ntpc;
  for (int T = 0; T < nt; T += 2) {
    const int t2 = (T + 2 < nt) ? T + 2 : nt - 1;   // tail: idempotent re-stage
    const int t3 = (T + 3 < nt) ? T + 3 : nt - 1;

    // p1: MFMA Q00(T); read B1(T) for p2
    RD_B(b1, 0, 1);
    PRIO1(); mma_quad(acc, a0, b0, 0, 0); PRIO0();
    VMCNT(8);  BARRIER();
    // p2: MFMA Q01(T); read A1(T) for p3; stage A0,B0(T+2)
    RD_A(a1, 0, 1);
    STAGE_A(t2, 0, 0); STAGE_B(t2, 0, 0);
    PRIO1(); mma_quad(acc, a0, b1, 0, 1); PRIO0();
    BARRIER();
    // p3: MFMA Q10(T); stage B1(T+2)
    STAGE_B(t2, 1, 0);
    PRIO1(); mma_quad(acc, a1, b0, 1, 0); PRIO0();
    VMCNT(10); BARRIER();
    // p4: MFMA Q11(T); read A0,B0(T+1) for p5; stage A1(T+2)
    RD_A(a0, 1, 0); RD_B(b0, 1, 0);
    STAGE_A(t2, 1, 0);
    PRIO1(); mma_quad(acc, a1, b1, 1, 1); PRIO0();
    VMCNT(10); BARRIER();
    // p5: MFMA Q00(T+1); read B1(T+1) for p6
    RD_B(b1, 1, 1);
    PRIO1(); mma_quad(acc, a0, b0, 0, 0); PRIO0();
    VMCNT(8);  BARRIER();
    // p6: MFMA Q01(T+1); read A1(T+1) for p7; stage A0,B0(T+3)
    RD_A(a1, 1, 1);
    STAGE_A(t3, 0, 1); STAGE_B(t3, 0, 1);
    PRIO1(); mma_quad(acc, a0, b1, 0, 1); PRIO0();
    BARRIER();
    // p7: MFMA Q10(T+1); stage B1(T+3)
    STAGE_B(t3, 1, 1);
    PRIO1(); mma_quad(acc, a1, b0, 1, 0); PRIO0();
    VMCNT(10); BARRIER();
    // p8: MFMA Q11(T+1); read A0,B0(T+2) for next p1; stage A1(T+3)
    RD_A(a0, 0, 0); RD_B(b0, 0, 0);
    STAGE_A(t3, 1, 1);
    PRIO1(); mma_quad(acc, a1, b1, 1, 1); PRIO0();
    VMCNT(10); BARRIER();
  }
#undef STAGE_A
#undef STAGE_B
#undef RD_A
#undef RD_B

  // epilogue: C/D layout col=lane&15, row=(lane>>4)*4+reg  [verified m89/m91]
#pragma unroll
  for (int m = 0; m < 8; ++m)
#pragma unroll
    for (int n = 0; n < 4; ++n) {
      size_t row0 = (size_t)(bm + m*32 + wr*16 + hi*4);
      size_t col  = (size_t)(bn + n*64 + wc*16 + fr);
#pragma unroll
      for (int r = 0; r < 4; ++r) {
        if (OUT16) {
          u16* Cz = (u16*)Cv + (size_t)blockIdx.z * (size_t)M * N;
          Cz[(row0 + r) * N + col] = f2bf(acc[m][n][r]);
        } else {
          float* Cz = (float*)Cv + (size_t)blockIdx.z * (size_t)M * N;
          Cz[(row0 + r) * N + col] = acc[m][n][r];
        }
      }
    }
}

// ============ softmax + precomputed dropout mask -> bf16 P ============
__global__ __launch_bounds__(256)
void softmax_dropout(const float* __restrict__ S, const u32* __restrict__ mask,
                     u16* __restrict__ P) {
  const int tid  = threadIdx.x;
  const int lane = tid & 63;
  const int w    = tid >> 6;
  const int row  = blockIdx.x * 4 + w;   // one row per wave
  const float4* Sr = (const float4*)(S + (size_t)row * MROWS);
  float4 v[16];
#pragma unroll
  for (int i = 0; i < 16; ++i) v[i] = Sr[i * 64 + lane];
  float m = -3.0e38f;
#pragma unroll
  for (int i = 0; i < 16; ++i)
    m = fmaxf(m, fmaxf(fmaxf(v[i].x, v[i].y), fmaxf(v[i].z, v[i].w)));
#pragma unroll
  for (int off = 32; off > 0; off >>= 1) m = fmaxf(m, __shfl_xor(m, off, 64));
  float s = 0.0f;
#pragma unroll
  for (int i = 0; i < 16; ++i) {
    v[i].x = __expf(v[i].x - m); v[i].y = __expf(v[i].y - m);
    v[i].z = __expf(v[i].z - m); v[i].w = __expf(v[i].w - m);
    s += v[i].x + v[i].y + v[i].z + v[i].w;
  }
#pragma unroll
  for (int off = 32; off > 0; off >>= 1) s += __shfl_xor(s, off, 64);
  const float inv = 2.0f / s;            // softmax normalize * 1/(1-p)
  u16* Pr = P + (size_t)row * MROWS;
  const u32* Mw = mask + (size_t)row * 128;
#pragma unroll
  for (int i = 0; i < 16; ++i) {
    int j0 = (i * 64 + lane) * 4;
    u32 word = Mw[j0 >> 5];
    int sh = j0 & 31;
    float e[4] = {v[i].x, v[i].y, v[i].z, v[i].w};
    u16x4 o;
#pragma unroll
    for (int c = 0; c < 4; ++c) {
      float val = ((word >> (sh + c)) & 1u) ? 0.0f : e[c] * inv;
      o[c] = f2bf(val);
    }
    *(u16x4*)(Pr + j0) = o;
  }
}

// ============ split-K reduction of bf16 partials ============
__global__ __launch_bounds__(256)
void reduce4(const u16* __restrict__ p, float4* __restrict__ out) {
  size_t i = (size_t)blockIdx.x * 256 + threadIdx.x;   // float4 index
  const size_t NP = (size_t)MROWS * DDIM;
  u16x4 a = *(const u16x4*)(p + i*4);
  u16x4 b = *(const u16x4*)(p + NP + i*4);
  u16x4 c = *(const u16x4*)(p + 2*NP + i*4);
  u16x4 d = *(const u16x4*)(p + 3*NP + i*4);
  float4 r;
  r.x = bf2f(a[0]) + bf2f(b[0]) + bf2f(c[0]) + bf2f(d[0]);
  r.y = bf2f(a[1]) + bf2f(b[1]) + bf2f(c[1]) + bf2f(d[1]);
  r.z = bf2f(a[2]) + bf2f(b[2]) + bf2f(c[2]) + bf2f(d[2]);
  r.w = bf2f(a[3]) + bf2f(b[3]) + bf2f(c[3]) + bf2f(d[3]);
  out[i] = r;
}

// ============ launch ============
extern "C" void kernel_launch(void* const* d_in, const int* in_sizes, int n_in,
                              void* d_out, int out_size, void* d_ws, size_t ws_size,
                              hipStream_t stream) {
  const float* x1 = (const float*)d_in[0];
  const float* x2 = (const float*)d_in[1];
  float* out = (float*)d_out;
  char* ws = (char*)d_ws;

  // ws layout (bytes):
  //   XA [0,24M) | XB [24M,48M) | VT [48M,56M) | S [56M,120M) | MASK [120M,122M)
  //   P (32M) overlays XA+XB after GEMM1 ; bf16 partials (33.6M) overlay S
  const size_t OFF_XB   = 25165824;
  const size_t OFF_VT   = 50331648;
  const size_t OFF_S    = 58720256;
  const size_t OFF_MASK = 125829120;
  const size_t NEED     = 127926272;
  if (ws_size < NEED) {
    hipMemsetAsync(d_out, 0x7F, (size_t)out_size * sizeof(float), stream);
    return;
  }
  u16*   XA = (u16*)(ws);
  u16*   XB = (u16*)(ws + OFF_XB);
  u16*   VT = (u16*)(ws + OFF_VT);
  float* S  = (float*)(ws + OFF_S);
  u16*   PT = (u16*)(ws + OFF_S);       // bf16 partials reuse S region
  u32*   MK = (u32*)(ws + OFF_MASK);
  u16*   P  = (u16*)(ws);               // reuses XA(+XB) region

  // mask words 0..262143 from expand(x1), 262144..524287 from expand(x2)
  expand3<<<2048, 256, 0, stream>>>((const float4*)x1, XA, 4.0f, 1, MK, 0u);
  expand3<<<2048, 256, 0, stream>>>((const float4*)x2, XB, 1.0f, 0, MK, 262144u);
  transpose_bf16<<<dim3(16, 64), 256, 0, stream>>>(x2, VT);
  // S = (4*x1) @ x2^T via 3-term expanded K = 3072
  gemm256<false><<<dim3(16, 16, 1), 512, 0, stream>>>(XA, XB, S, 4096, 4096, 3072, 48);
  softmax_dropout<<<1024, 256, 0, stream>>>(S, MK, P);
  // O = P @ V: split-K x4 (K=4096, 16 tiles/chunk), bf16 partials, then reduce
  gemm256<true><<<dim3(4, 16, 4), 512, 0, stream>>>(P, VT, PT, 4096, 1024, 4096, 16);
  reduce4<<<4096, 256, 0, stream>>>(PT, (float4*)out);
}

// Round 6
// 187.039 us; speedup vs baseline: 1.1004x; 1.0266x over previous
//
#include <hip/hip_runtime.h>

typedef unsigned short u16;
typedef unsigned int   u32;
typedef __attribute__((ext_vector_type(4))) float f32x4;
typedef __attribute__((ext_vector_type(8))) short bf16x8;
typedef __attribute__((ext_vector_type(8))) unsigned short u16x8;
typedef __attribute__((ext_vector_type(4))) unsigned short u16x4;

#define MROWS 4096
#define DDIM  1024

__device__ __forceinline__ u16 f2bf(float f) {
  u32 u = __float_as_uint(f);
  return (u16)((u + 0x7FFFu + ((u >> 16) & 1u)) >> 16);   // RNE
}
__device__ __forceinline__ float bf2f(u16 h) { return __uint_as_float(((u32)h) << 16); }

// ---------- JAX partitionable threefry2x32, key(42): bits(n) = o0^o1 ----------
__device__ __forceinline__ u32 rotl32(u32 x, int r) { return (x << r) | (x >> (32 - r)); }
__device__ __forceinline__ u32 threefry_bits(u32 n) {
  const u32 K0 = 0u, K1 = 42u, K2 = 0x1BD11BDAu ^ 0u ^ 42u;
  u32 x0 = K0;
  u32 x1 = n + K1;
#define TF4(a,b,c,d) \
  x0 += x1; x1 = rotl32(x1, a); x1 ^= x0; \
  x0 += x1; x1 = rotl32(x1, b); x1 ^= x0; \
  x0 += x1; x1 = rotl32(x1, c); x1 ^= x0; \
  x0 += x1; x1 = rotl32(x1, d); x1 ^= x0;
  TF4(13,15,26,6);  x0 += K1; x1 += K2 + 1u;
  TF4(17,29,16,24); x0 += K2; x1 += K0 + 2u;
  TF4(13,15,26,6);  x0 += K0; x1 += K1 + 3u;
  TF4(17,29,16,24); x0 += K1; x1 += K2 + 4u;
  TF4(13,15,26,6);  x0 += K2; x1 += K0 + 5u;
#undef TF4
  return x0 ^ x1;
}

// ============ expand x1: 3-term hi/lo split [ah,ah,al], scale folded ============
__global__ __launch_bounds__(256)
void expandA(const float4* __restrict__ x, u16* __restrict__ out) {
  int t = blockIdx.x * 256 + threadIdx.x;      // 524288 threads, 8 floats each
  float4 v0 = x[(size_t)t * 2], v1 = x[(size_t)t * 2 + 1];
  float vv[8] = {v0.x*4.f, v0.y*4.f, v0.z*4.f, v0.w*4.f,
                 v1.x*4.f, v1.y*4.f, v1.z*4.f, v1.w*4.f};
  u16 o[24];
#pragma unroll
  for (int j = 0; j < 8; ++j) {
    u16 h = f2bf(vv[j]);
    u16 l = f2bf(vv[j] - bf2f(h));             // Sterbenz-exact residual, RNE
    o[3*j] = h; o[3*j+1] = h; o[3*j+2] = l;
  }
  u16x8* dst = (u16x8*)(out + (size_t)t * 24);
#pragma unroll
  for (int q = 0; q < 3; ++q) {
    u16x8 wv;
#pragma unroll
    for (int j = 0; j < 8; ++j) wv[j] = o[q*8+j];
    dst[q] = wv;
  }
}

// ============ fused x2 pass: XB expanded [bh,bl,bh] + VT transpose ============
// grid (16 dt, 64 kt), 256 thr. Reads x2 once.
__global__ __launch_bounds__(256)
void castB_transpose(const float* __restrict__ x2, u16* __restrict__ XB,
                     u16* __restrict__ VT) {
  __shared__ float tile[64][65];
  int tid = threadIdx.x;
  int dt = blockIdx.x;   // 16 D-tiles
  int kt = blockIdx.y;   // 64 K-tiles
#pragma unroll
  for (int it = 0; it < 16; ++it) {
    int lin = it * 256 + tid;
    int r = lin >> 6, c = lin & 63;
    tile[r][c] = x2[(size_t)(kt*64 + r) * DDIM + dt*64 + c];
  }
  __syncthreads();
  // XB: thread owns 2 rows x 8 cols; writes 24 contiguous u16 (3 vectors)
#pragma unroll
  for (int itr = 0; itr < 2; ++itr) {
    int r  = (tid >> 3) + itr * 32;     // 0..63
    int c0 = (tid & 7) * 8;
    u16 o[24];
#pragma unroll
    for (int j = 0; j < 8; ++j) {
      float v = tile[r][c0 + j];
      u16 h = f2bf(v);
      u16 l = f2bf(v - bf2f(h));
      o[3*j] = h; o[3*j+1] = l; o[3*j+2] = h;
    }
    u16x8* dst = (u16x8*)(XB + (size_t)(kt*64 + r) * 3072 + (size_t)(dt*64 + c0) * 3);
#pragma unroll
    for (int q = 0; q < 3; ++q) {
      u16x8 wv;
#pragma unroll
      for (int j = 0; j < 8; ++j) wv[j] = o[q*8+j];
      dst[q] = wv;
    }
  }
  // VT[d][k] = bf16(x2[k][d])
#pragma unroll
  for (int it = 0; it < 16; ++it) {
    int lin = it * 256 + tid;
    int dr = lin >> 6, kc = lin & 63;
    VT[(size_t)(dt*64 + dr) * MROWS + kt*64 + kc] = f2bf(tile[kc][dr]);
  }
}

// ============ 256x256 pipelined 8-phase GEMM (round-5 schedule, unchanged) ============
__device__ __forceinline__ void gload16(const u16* g, u16* l) {
  __builtin_amdgcn_global_load_lds(
      (const __attribute__((address_space(1))) void*)g,
      (__attribute__((address_space(3))) void*)l, 16, 0, 0);
}

#define BARRIER() do { asm volatile("" ::: "memory"); __builtin_amdgcn_s_barrier(); \
                       asm volatile("" ::: "memory"); } while (0)
#define VMCNT(N)  asm volatile("s_waitcnt vmcnt(" #N ")" ::: "memory")
#define PRIO1()   __builtin_amdgcn_s_setprio(1)
#define PRIO0()   __builtin_amdgcn_s_setprio(0)

__device__ __forceinline__ void mma_quad(f32x4 (&acc)[8][4], const bf16x8 (&aF)[4][2],
                                         const bf16x8 (&bF)[2][2], int MH, int NH) {
#pragma unroll
  for (int kx = 0; kx < 2; ++kx)
#pragma unroll
    for (int m = 0; m < 4; ++m)
#pragma unroll
      for (int n = 0; n < 2; ++n)
        acc[MH*4+m][NH*2+n] = __builtin_amdgcn_mfma_f32_16x16x32_bf16(
            aF[m][kx], bF[n][kx], acc[MH*4+m][NH*2+n], 0, 0, 0);
}

// LDS u16 layout: A(d,h) = (d*2+h)*8192 ; B(d,h) = 32768 + (d*2+h)*8192
template <bool OUT16, bool REMAP>
__global__ __launch_bounds__(512, 2)
void gemm256(const u16* __restrict__ A, const u16* __restrict__ Bt, void* __restrict__ Cv,
             int M, int N, int K, int ntpc) {
  __shared__ u16 smem[65536];   // 128 KiB
  const int tid = threadIdx.x;
  const int lane = tid & 63;
  const int w = tid >> 6;
  const int wr = w >> 2;          // 0..1
  const int wc = w & 3;           // 0..3
  const int fr = lane & 15;
  const int hi = lane >> 4;

  // REMAP (G2, grid 4x16xZ): group 2 by-rows per XCD -> L2 holds the k-window
  // of 2 A-panels x 4 B-panels instead of 16 thrashing A-panels.
  int bxi, byi;
  if (REMAP) {
    const int id0 = blockIdx.y * gridDim.x + blockIdx.x;  // 0..63
    const int c = id0 & 7, j = id0 >> 3;                  // xcd = c (z adds mult. of 64)
    bxi = j >> 1;
    byi = c * 2 + (j & 1);
  } else {
    bxi = blockIdx.x; byi = blockIdx.y;
  }

  const long bm = (long)byi * 256;
  const long bn = (long)bxi * 256;
  const size_t kcol0 = (size_t)blockIdx.z * ntpc * 64;

  const int srow = tid >> 3;
  const int scol = (((tid & 7) ^ (srow & 7)) << 3);
  const u16* Abase = A  + (size_t)(bm + srow) * K + kcol0 + scol;
  const u16* Bbase = Bt + (size_t)(bn + srow) * K + kcol0 + scol;

  const int csw0 = ((hi)     ^ (fr & 7)) << 3;
  const int csw1 = ((4 + hi) ^ (fr & 7)) << 3;
  const int arow = (wr*16 + fr) * 64;
  const int brow = (wc*16 + fr) * 64;

#define RD_A(dst, D, H) do { \
    const u16* _b0 = smem + ((D)*2+(H))*8192 + arow + csw0; \
    const u16* _b1 = smem + ((D)*2+(H))*8192 + arow + csw1; \
    dst[0][0] = *(const bf16x8*)(_b0);        dst[0][1] = *(const bf16x8*)(_b1); \
    dst[1][0] = *(const bf16x8*)(_b0 + 2048); dst[1][1] = *(const bf16x8*)(_b1 + 2048); \
    dst[2][0] = *(const bf16x8*)(_b0 + 4096); dst[2][1] = *(const bf16x8*)(_b1 + 4096); \
    dst[3][0] = *(const bf16x8*)(_b0 + 6144); dst[3][1] = *(const bf16x8*)(_b1 + 6144); } while (0)
#define RD_B(dst, D, H) do { \
    const u16* _b0 = smem + 32768 + ((D)*2+(H))*8192 + brow + csw0; \
    const u16* _b1 = smem + 32768 + ((D)*2+(H))*8192 + brow + csw1; \
    dst[0][0] = *(const bf16x8*)(_b0);        dst[0][1] = *(const bf16x8*)(_b1); \
    dst[1][0] = *(const bf16x8*)(_b0 + 4096); dst[1][1] = *(const bf16x8*)(_b1 + 4096); } while (0)

  f32x4 acc[8][4];
#pragma unroll
  for (int m = 0; m < 8; ++m)
#pragma unroll
    for (int n = 0; n < 4; ++n) acc[m][n] = (f32x4){0.f, 0.f, 0.f, 0.f};
  bf16x8 a0[4][2], a1[4][2], b0[2][2], b1[2][2];

#define STAGE_A(TAU,H,D) do { \
    const u16* _s = Abase + (size_t)(H)*128*K + (size_t)(TAU)*64; \
    u16* _d = smem + ((D)*2+(H))*8192 + tid*8; \
    gload16(_s, _d); gload16(_s + (size_t)64*K, _d + 4096); } while (0)
#define STAGE_B(TAU,H,D) do { \
    const u16* _s = Bbase + (size_t)(H)*128*K + (size_t)(TAU)*64; \
    u16* _d = smem + 32768 + ((D)*2+(H))*8192 + tid*8; \
    gload16(_s, _d); gload16(_s + (size_t)64*K, _d + 4096); } while (0)

  // ---- prologue: prime LDS + register pipeline ----
  STAGE_A(0,0,0); STAGE_B(0,0,0);
  VMCNT(0); BARRIER();
  RD_A(a0, 0, 0); RD_B(b0, 0, 0);
  STAGE_B(0,1,0);
  STAGE_A(0,1,0);
  STAGE_A(1,0,1); STAGE_B(1,0,1);
  STAGE_B(1,1,1);
  STAGE_A(1,1,1);
  VMCNT(10); BARRIER();

  const int nt = ntpc;
  for (int T = 0; T < nt; T += 2) {
    const int t2 = (T + 2 < nt) ? T + 2 : nt - 1;
    const int t3 = (T + 3 < nt) ? T + 3 : nt - 1;

    // p1: MFMA Q00(T); read B1(T) for p2
    RD_B(b1, 0, 1);
    PRIO1(); mma_quad(acc, a0, b0, 0, 0); PRIO0();
    VMCNT(8);  BARRIER();
    // p2: MFMA Q01(T); read A1(T); stage A0,B0(T+2)
    RD_A(a1, 0, 1);
    STAGE_A(t2, 0, 0); STAGE_B(t2, 0, 0);
    PRIO1(); mma_quad(acc, a0, b1, 0, 1); PRIO0();
    BARRIER();
    // p3: MFMA Q10(T); stage B1(T+2)
    STAGE_B(t2, 1, 0);
    PRIO1(); mma_quad(acc, a1, b0, 1, 0); PRIO0();
    VMCNT(10); BARRIER();
    // p4: MFMA Q11(T); read A0,B0(T+1); stage A1(T+2)
    RD_A(a0, 1, 0); RD_B(b0, 1, 0);
    STAGE_A(t2, 1, 0);
    PRIO1(); mma_quad(acc, a1, b1, 1, 1); PRIO0();
    VMCNT(10); BARRIER();
    // p5: MFMA Q00(T+1); read B1(T+1)
    RD_B(b1, 1, 1);
    PRIO1(); mma_quad(acc, a0, b0, 0, 0); PRIO0();
    VMCNT(8);  BARRIER();
    // p6: MFMA Q01(T+1); read A1(T+1); stage A0,B0(T+3)
    RD_A(a1, 1, 1);
    STAGE_A(t3, 0, 1); STAGE_B(t3, 0, 1);
    PRIO1(); mma_quad(acc, a0, b1, 0, 1); PRIO0();
    BARRIER();
    // p7: MFMA Q10(T+1); stage B1(T+3)
    STAGE_B(t3, 1, 1);
    PRIO1(); mma_quad(acc, a1, b0, 1, 0); PRIO0();
    VMCNT(10); BARRIER();
    // p8: MFMA Q11(T+1); read A0,B0(T+2); stage A1(T+3)
    RD_A(a0, 0, 0); RD_B(b0, 0, 0);
    STAGE_A(t3, 1, 1);
    PRIO1(); mma_quad(acc, a1, b1, 1, 1); PRIO0();
    VMCNT(10); BARRIER();
  }
#undef STAGE_A
#undef STAGE_B
#undef RD_A
#undef RD_B

  // epilogue: C/D layout col=lane&15, row=(lane>>4)*4+reg  [verified m89/m91]
#pragma unroll
  for (int m = 0; m < 8; ++m)
#pragma unroll
    for (int n = 0; n < 4; ++n) {
      size_t row0 = (size_t)(bm + m*32 + wr*16 + hi*4);
      size_t col  = (size_t)(bn + n*64 + wc*16 + fr);
#pragma unroll
      for (int r = 0; r < 4; ++r) {
        if (OUT16) {
          u16* Cz = (u16*)Cv + (size_t)blockIdx.z * (size_t)M * N;
          Cz[(row0 + r) * N + col] = f2bf(acc[m][n][r]);
        } else {
          float* Cz = (float*)Cv + (size_t)blockIdx.z * (size_t)M * N;
          Cz[(row0 + r) * N + col] = acc[m][n][r];
        }
      }
    }
}

// ============ softmax + INLINE threefry dropout -> bf16 P ============
// Threefry VALU (~19us chip-wide) hides under this kernel's streaming loads:
// no barriers after load, high occupancy, separate pipes (m114).
__global__ __launch_bounds__(256)
void softmax_dropout(const float* __restrict__ S, u16* __restrict__ P) {
  const int tid  = threadIdx.x;
  const int lane = tid & 63;
  const int w    = tid >> 6;
  const int row  = blockIdx.x * 4 + w;   // one row per wave
  const float4* Sr = (const float4*)(S + (size_t)row * MROWS);
  float4 v[16];
#pragma unroll
  for (int i = 0; i < 16; ++i) v[i] = Sr[i * 64 + lane];
  float m = -3.0e38f;
#pragma unroll
  for (int i = 0; i < 16; ++i)
    m = fmaxf(m, fmaxf(fmaxf(v[i].x, v[i].y), fmaxf(v[i].z, v[i].w)));
#pragma unroll
  for (int off = 32; off > 0; off >>= 1) m = fmaxf(m, __shfl_xor(m, off, 64));
  float s = 0.0f;
#pragma unroll
  for (int i = 0; i < 16; ++i) {
    v[i].x = __expf(v[i].x - m); v[i].y = __expf(v[i].y - m);
    v[i].z = __expf(v[i].z - m); v[i].w = __expf(v[i].w - m);
    s += v[i].x + v[i].y + v[i].z + v[i].w;
  }
#pragma unroll
  for (int off = 32; off > 0; off >>= 1) s += __shfl_xor(s, off, 64);
  const float inv = 2.0f / s;            // softmax normalize * 1/(1-p)
  u16* Pr = P + (size_t)row * MROWS;
#pragma unroll
  for (int i = 0; i < 16; ++i) {
    int j0 = (i * 64 + lane) * 4;
    u32 base = (u32)row * 4096u + (u32)j0;
    float e[4] = {v[i].x, v[i].y, v[i].z, v[i].w};
    u16x4 o;
#pragma unroll
    for (int c = 0; c < 4; ++c) {
      u32 bits = threefry_bits(base + (u32)c);
      float val = (bits & 0x80000000u) ? 0.0f : e[c] * inv;   // uniform<0.5 == MSB 0
      o[c] = f2bf(val);
    }
    *(u16x4*)(Pr + j0) = o;
  }
}

// ============ split-K reduction of bf16 partials ============
__global__ __launch_bounds__(256)
void reduce4(const u16* __restrict__ p, float4* __restrict__ out) {
  size_t i = (size_t)blockIdx.x * 256 + threadIdx.x;   // float4 index
  const size_t NP = (size_t)MROWS * DDIM;
  u16x4 a = *(const u16x4*)(p + i*4);
  u16x4 b = *(const u16x4*)(p + NP + i*4);
  u16x4 c = *(const u16x4*)(p + 2*NP + i*4);
  u16x4 d = *(const u16x4*)(p + 3*NP + i*4);
  float4 r;
  r.x = bf2f(a[0]) + bf2f(b[0]) + bf2f(c[0]) + bf2f(d[0]);
  r.y = bf2f(a[1]) + bf2f(b[1]) + bf2f(c[1]) + bf2f(d[1]);
  r.z = bf2f(a[2]) + bf2f(b[2]) + bf2f(c[2]) + bf2f(d[2]);
  r.w = bf2f(a[3]) + bf2f(b[3]) + bf2f(c[3]) + bf2f(d[3]);
  out[i] = r;
}

// ============ launch ============
extern "C" void kernel_launch(void* const* d_in, const int* in_sizes, int n_in,
                              void* d_out, int out_size, void* d_ws, size_t ws_size,
                              hipStream_t stream) {
  const float* x1 = (const float*)d_in[0];
  const float* x2 = (const float*)d_in[1];
  float* out = (float*)d_out;
  char* ws = (char*)d_ws;

  // ws layout (bytes):
  //   XA [0,24M) | XB [24M,48M) | VT [48M,56M) | S [56M,120M)
  //   P (32M) overlays XA+XB after GEMM1 ; bf16 partials (32M) overlay S
  const size_t OFF_XB   = 25165824;
  const size_t OFF_VT   = 50331648;
  const size_t OFF_S    = 58720256;
  const size_t NEED     = 125829120;
  if (ws_size < NEED) {
    hipMemsetAsync(d_out, 0x7F, (size_t)out_size * sizeof(float), stream);
    return;
  }
  u16*   XA = (u16*)(ws);
  u16*   XB = (u16*)(ws + OFF_XB);
  u16*   VT = (u16*)(ws + OFF_VT);
  float* S  = (float*)(ws + OFF_S);
  u16*   PT = (u16*)(ws + OFF_S);       // bf16 partials reuse S region
  u16*   P  = (u16*)(ws);               // reuses XA(+XB) region

  expandA<<<2048, 256, 0, stream>>>((const float4*)x1, XA);
  castB_transpose<<<dim3(16, 64), 256, 0, stream>>>(x2, XB, VT);
  // S = (4*x1) @ x2^T via 3-term expanded K = 3072
  gemm256<false, false><<<dim3(16, 16, 1), 512, 0, stream>>>(XA, XB, S, 4096, 4096, 3072, 48);
  softmax_dropout<<<1024, 256, 0, stream>>>(S, P);
  // O = P @ V: split-K x4 (K=4096, 16 tiles/chunk), bf16 partials, then reduce
  gemm256<true, true><<<dim3(4, 16, 4), 512, 0, stream>>>(P, VT, PT, 4096, 1024, 4096, 16);
  reduce4<<<4096, 256, 0, stream>>>(PT, (float4*)out);
}

// Round 7
// 186.351 us; speedup vs baseline: 1.1045x; 1.0037x over previous
//
#include <hip/hip_runtime.h>

typedef unsigned short u16;
typedef unsigned int   u32;
typedef __attribute__((ext_vector_type(4))) float f32x4;
typedef __attribute__((ext_vector_type(8))) short bf16x8;
typedef __attribute__((ext_vector_type(8))) unsigned short u16x8;
typedef __attribute__((ext_vector_type(4))) unsigned short u16x4;

#define MROWS 4096
#define DDIM  1024

__device__ __forceinline__ u16 f2bf(float f) {
  u32 u = __float_as_uint(f);
  return (u16)((u + 0x7FFFu + ((u >> 16) & 1u)) >> 16);   // RNE
}
__device__ __forceinline__ float bf2f(u16 h) { return __uint_as_float(((u32)h) << 16); }

// ---------- JAX partitionable threefry2x32, key(42): bits(n) = o0^o1 ----------
__device__ __forceinline__ u32 rotl32(u32 x, int r) { return (x << r) | (x >> (32 - r)); }
__device__ __forceinline__ u32 threefry_bits(u32 n) {
  const u32 K0 = 0u, K1 = 42u, K2 = 0x1BD11BDAu ^ 0u ^ 42u;
  u32 x0 = K0;
  u32 x1 = n + K1;
#define TF4(a,b,c,d) \
  x0 += x1; x1 = rotl32(x1, a); x1 ^= x0; \
  x0 += x1; x1 = rotl32(x1, b); x1 ^= x0; \
  x0 += x1; x1 = rotl32(x1, c); x1 ^= x0; \
  x0 += x1; x1 = rotl32(x1, d); x1 ^= x0;
  TF4(13,15,26,6);  x0 += K1; x1 += K2 + 1u;
  TF4(17,29,16,24); x0 += K2; x1 += K0 + 2u;
  TF4(13,15,26,6);  x0 += K0; x1 += K1 + 3u;
  TF4(17,29,16,24); x0 += K1; x1 += K2 + 4u;
  TF4(13,15,26,6);  x0 += K2; x1 += K0 + 5u;
#undef TF4
  return x0 ^ x1;
}

// ============ expand x1: 3-term hi/lo split [ah,ah,al], scale folded ============
__global__ __launch_bounds__(256)
void expandA(const float4* __restrict__ x, u16* __restrict__ out) {
  int t = blockIdx.x * 256 + threadIdx.x;      // 524288 threads, 8 floats each
  float4 v0 = x[(size_t)t * 2], v1 = x[(size_t)t * 2 + 1];
  float vv[8] = {v0.x*4.f, v0.y*4.f, v0.z*4.f, v0.w*4.f,
                 v1.x*4.f, v1.y*4.f, v1.z*4.f, v1.w*4.f};
  u16 o[24];
#pragma unroll
  for (int j = 0; j < 8; ++j) {
    u16 h = f2bf(vv[j]);
    u16 l = f2bf(vv[j] - bf2f(h));             // Sterbenz-exact residual, RNE
    o[3*j] = h; o[3*j+1] = h; o[3*j+2] = l;
  }
  u16x8* dst = (u16x8*)(out + (size_t)t * 24);
#pragma unroll
  for (int q = 0; q < 3; ++q) {
    u16x8 wv;
#pragma unroll
    for (int j = 0; j < 8; ++j) wv[j] = o[q*8+j];
    dst[q] = wv;
  }
}

// ============ fused x2 pass: XB expanded [bh,bl,bh] + VT transpose ============
__global__ __launch_bounds__(256)
void castB_transpose(const float* __restrict__ x2, u16* __restrict__ XB,
                     u16* __restrict__ VT) {
  __shared__ float tile[64][65];
  int tid = threadIdx.x;
  int dt = blockIdx.x;   // 16 D-tiles
  int kt = blockIdx.y;   // 64 K-tiles
#pragma unroll
  for (int it = 0; it < 16; ++it) {
    int lin = it * 256 + tid;
    int r = lin >> 6, c = lin & 63;
    tile[r][c] = x2[(size_t)(kt*64 + r) * DDIM + dt*64 + c];
  }
  __syncthreads();
  // XB: thread owns 2 rows x 8 cols; 48B contiguous per row-chunk
#pragma unroll
  for (int itr = 0; itr < 2; ++itr) {
    int r  = (tid >> 3) + itr * 32;
    int c0 = (tid & 7) * 8;
    u16 o[24];
#pragma unroll
    for (int j = 0; j < 8; ++j) {
      float v = tile[r][c0 + j];
      u16 h = f2bf(v);
      u16 l = f2bf(v - bf2f(h));
      o[3*j] = h; o[3*j+1] = l; o[3*j+2] = h;
    }
    u16x8* dst = (u16x8*)(XB + (size_t)(kt*64 + r) * 3072 + (size_t)(dt*64 + c0) * 3);
#pragma unroll
    for (int q = 0; q < 3; ++q) {
      u16x8 wv;
#pragma unroll
      for (int j = 0; j < 8; ++j) wv[j] = o[q*8+j];
      dst[q] = wv;
    }
  }
  // VT[d][k] = bf16(x2[k][d]); 16B per thread store
#pragma unroll
  for (int it = 0; it < 2; ++it) {
    int dr  = (tid >> 3) + it * 32;
    int kc0 = (tid & 7) * 8;
    u16x8 wv;
#pragma unroll
    for (int j = 0; j < 8; ++j) wv[j] = f2bf(tile[kc0 + j][dr]);
    *(u16x8*)(VT + (size_t)(dt*64 + dr) * MROWS + kt*64 + kc0) = wv;
  }
}

// ============ 256x256 pipelined 8-phase GEMM body ============
// One-phase-ahead register pipeline, balanced LDS reads 8/4/4/8 per half-iter,
// one barrier/phase, counted vmcnt (FIFO-derived), setprio on MFMA.
__device__ __forceinline__ void gload16(const u16* g, u16* l) {
  __builtin_amdgcn_global_load_lds(
      (const __attribute__((address_space(1))) void*)g,
      (__attribute__((address_space(3))) void*)l, 16, 0, 0);
}

#define BARRIER() do { asm volatile("" ::: "memory"); __builtin_amdgcn_s_barrier(); \
                       asm volatile("" ::: "memory"); } while (0)
#define VMCNT(N)  asm volatile("s_waitcnt vmcnt(" #N ")" ::: "memory")
#define PRIO1()   __builtin_amdgcn_s_setprio(1)
#define PRIO0()   __builtin_amdgcn_s_setprio(0)

__device__ __forceinline__ void mma_quad(f32x4 (&acc)[8][4], const bf16x8 (&aF)[4][2],
                                         const bf16x8 (&bF)[2][2], int MH, int NH) {
#pragma unroll
  for (int kx = 0; kx < 2; ++kx)
#pragma unroll
    for (int m = 0; m < 4; ++m)
#pragma unroll
      for (int n = 0; n < 2; ++n)
        acc[MH*4+m][NH*2+n] = __builtin_amdgcn_mfma_f32_16x16x32_bf16(
            aF[m][kx], bF[n][kx], acc[MH*4+m][NH*2+n], 0, 0, 0);
}

// LDS u16 layout: A(d,h) = (d*2+h)*8192 ; B(d,h) = 32768 + (d*2+h)*8192
template <bool OUT16, bool REMAP>
__device__ __forceinline__ void gemm_body(const u16* __restrict__ A,
                                          const u16* __restrict__ Bt,
                                          void* __restrict__ Cv,
                                          int M, int N, int K, int ntpc) {
  __shared__ u16 smem[65536];   // 128 KiB
  const int tid = threadIdx.x;
  const int lane = tid & 63;
  const int w = tid >> 6;
  const int wr = w >> 2;          // 0..1
  const int wc = w & 3;           // 0..3
  const int fr = lane & 15;
  const int hi = lane >> 4;

  int bxi, byi;
  if (REMAP) {  // G2 (grid 4x16xZ): 2 by-rows per XCD -> L2-resident k-window
    const int id0 = blockIdx.y * gridDim.x + blockIdx.x;  // 0..63
    const int c = id0 & 7, j = id0 >> 3;
    bxi = j >> 1;
    byi = c * 2 + (j & 1);
  } else {
    bxi = blockIdx.x; byi = blockIdx.y;
  }

  const long bm = (long)byi * 256;
  const long bn = (long)bxi * 256;
  const size_t kcol0 = (size_t)blockIdx.z * ntpc * 64;

  const int srow = tid >> 3;
  const int scol = (((tid & 7) ^ (srow & 7)) << 3);
  const u16* Abase = A  + (size_t)(bm + srow) * K + kcol0 + scol;
  const u16* Bbase = Bt + (size_t)(bn + srow) * K + kcol0 + scol;

  const int csw0 = ((hi)     ^ (fr & 7)) << 3;
  const int csw1 = ((4 + hi) ^ (fr & 7)) << 3;
  const int arow = (wr*16 + fr) * 64;
  const int brow = (wc*16 + fr) * 64;

  // RD_A2: 2 M-frags (4 ds_read_b128); RD_B: both N-frags (4)
#define RD_A2(dst, D, H, M0) do { \
    const u16* _p = smem + ((D)*2+(H))*8192 + arow + (M0)*2048; \
    dst[M0][0]   = *(const bf16x8*)(_p + csw0); \
    dst[M0][1]   = *(const bf16x8*)(_p + csw1); \
    dst[M0+1][0] = *(const bf16x8*)(_p + 2048 + csw0); \
    dst[M0+1][1] = *(const bf16x8*)(_p + 2048 + csw1); } while (0)
#define RD_B(dst, D, H) do { \
    const u16* _p = smem + 32768 + ((D)*2+(H))*8192 + brow; \
    dst[0][0] = *(const bf16x8*)(_p + csw0); \
    dst[0][1] = *(const bf16x8*)(_p + csw1); \
    dst[1][0] = *(const bf16x8*)(_p + 4096 + csw0); \
    dst[1][1] = *(const bf16x8*)(_p + 4096 + csw1); } while (0)

  f32x4 acc[8][4];
#pragma unroll
  for (int m = 0; m < 8; ++m)
#pragma unroll
    for (int n = 0; n < 4; ++n) acc[m][n] = (f32x4){0.f, 0.f, 0.f, 0.f};
  bf16x8 a0[4][2], a1[4][2], b0[2][2], b1[2][2];

#define STAGE_A(TAU,H,D) do { \
    const u16* _s = Abase + (size_t)(H)*128*K + (size_t)(TAU)*64; \
    u16* _d = smem + ((D)*2+(H))*8192 + tid*8; \
    gload16(_s, _d); gload16(_s + (size_t)64*K, _d + 4096); } while (0)
#define STAGE_B(TAU,H,D) do { \
    const u16* _s = Bbase + (size_t)(H)*128*K + (size_t)(TAU)*64; \
    u16* _d = smem + 32768 + ((D)*2+(H))*8192 + tid*8; \
    gload16(_s, _d); gload16(_s + (size_t)64*K, _d + 4096); } while (0)

  // ---- prologue: tile0 landed; tile1's 8 loads left in flight (FIFO invariant) ----
  STAGE_A(0,0,0); STAGE_B(0,0,0);
  STAGE_B(0,1,0); STAGE_A(0,1,0);
  VMCNT(0); BARRIER();
  RD_A2(a0,0,0,0); RD_A2(a0,0,0,2); RD_B(b0,0,0);   // regs for p1
  STAGE_A(1,0,1); STAGE_B(1,0,1);                   // A0,B0(1)
  STAGE_B(1,1,1);                                   // B1(1)
  STAGE_A(1,1,1);                                   // A1(1)
  BARRIER();                                        // 8 outstanding at loop-top

  const int nt = ntpc;
  for (int T = 0; T < nt; T += 2) {
    const int t2 = (T + 2 < nt) ? T + 2 : nt - 1;   // tail: idempotent re-stage
    const int t3 = (T + 3 < nt) ? T + 3 : nt - 1;

    // p1: MFMA Q00(T)[a0,b0]; read b1(T), a1[01](T)           (8 reads)
    RD_B(b1, 0, 1); RD_A2(a1, 0, 1, 0);
    PRIO1(); mma_quad(acc, a0, b0, 0, 0); PRIO0();
    BARRIER();
    // p2: MFMA Q01(T)[a0,b1]; read a1[23](T); stage A0,B0(T+2) (4 reads)
    RD_A2(a1, 0, 1, 2);
    STAGE_A(t2, 0, 0); STAGE_B(t2, 0, 0);
    PRIO1(); mma_quad(acc, a0, b1, 0, 1); PRIO0();
    VMCNT(10); BARRIER();                 // drains A0(T+1) for p3
    // p3: MFMA Q10(T)[a1,b0]; read a0[01](T+1); stage B1(T+2)  (4 reads)
    RD_A2(a0, 1, 0, 0);
    STAGE_B(t2, 1, 0);
    PRIO1(); mma_quad(acc, a1, b0, 1, 0); PRIO0();
    VMCNT(10); BARRIER();                 // drains B0(T+1) for p4
    // p4: MFMA Q11(T)[a1,b1]; read a0[23](T+1), b0(T+1); stage A1(T+2) (8 reads)
    RD_A2(a0, 1, 0, 2); RD_B(b0, 1, 0);
    STAGE_A(t2, 1, 0);
    PRIO1(); mma_quad(acc, a1, b1, 1, 1); PRIO0();
    VMCNT(8); BARRIER();                  // drains B1(T+1), A1(T+1) for p5
    // p5: MFMA Q00(T+1)[a0,b0]; read b1(T+1), a1[01](T+1)      (8 reads)
    RD_B(b1, 1, 1); RD_A2(a1, 1, 1, 0);
    PRIO1(); mma_quad(acc, a0, b0, 0, 0); PRIO0();
    BARRIER();
    // p6: MFMA Q01(T+1)[a0,b1]; read a1[23](T+1); stage A0,B0(T+3) (4 reads)
    RD_A2(a1, 1, 1, 2);
    STAGE_A(t3, 0, 1); STAGE_B(t3, 0, 1);
    PRIO1(); mma_quad(acc, a0, b1, 0, 1); PRIO0();
    VMCNT(10); BARRIER();                 // drains A0(T+2) for p7
    // p7: MFMA Q10(T+1)[a1,b0]; read a0[01](T+2); stage B1(T+3) (4 reads)
    RD_A2(a0, 0, 0, 0);
    STAGE_B(t3, 1, 1);
    PRIO1(); mma_quad(acc, a1, b0, 1, 0); PRIO0();
    VMCNT(10); BARRIER();                 // drains B0(T+2) for p8
    // p8: MFMA Q11(T+1)[a1,b1]; read a0[23](T+2), b0(T+2); stage A1(T+3) (8 reads)
    RD_A2(a0, 0, 0, 2); RD_B(b0, 0, 0);
    STAGE_A(t3, 1, 1);
    PRIO1(); mma_quad(acc, a1, b1, 1, 1); PRIO0();
    VMCNT(8); BARRIER();                  // drains B1(T+2), A1(T+2) for next p1
  }
#undef STAGE_A
#undef STAGE_B
#undef RD_A2
#undef RD_B

  // epilogue: C/D layout col=lane&15, row=(lane>>4)*4+reg  [verified m89/m91]
#pragma unroll
  for (int m = 0; m < 8; ++m)
#pragma unroll
    for (int n = 0; n < 4; ++n) {
      size_t row0 = (size_t)(bm + m*32 + wr*16 + hi*4);
      size_t col  = (size_t)(bn + n*64 + wc*16 + fr);
#pragma unroll
      for (int r = 0; r < 4; ++r) {
        if (OUT16) {
          u16* Cz = (u16*)Cv + (size_t)blockIdx.z * (size_t)M * N;
          Cz[(row0 + r) * N + col] = f2bf(acc[m][n][r]);
        } else {
          float* Cz = (float*)Cv + (size_t)blockIdx.z * (size_t)M * N;
          Cz[(row0 + r) * N + col] = acc[m][n][r];
        }
      }
    }
}

__global__ __launch_bounds__(512, 2)
void gemm_qk(const u16* __restrict__ A, const u16* __restrict__ Bt,
             void* __restrict__ Cv, int M, int N, int K, int ntpc) {
  gemm_body<false, false>(A, Bt, Cv, M, N, K, ntpc);
}
__global__ __launch_bounds__(512, 2)
void gemm_pv(const u16* __restrict__ A, const u16* __restrict__ Bt,
             void* __restrict__ Cv, int M, int N, int K, int ntpc) {
  gemm_body<true, true>(A, Bt, Cv, M, N, K, ntpc);
}

// ============ softmax + inline threefry dropout -> bf16 P ============
__global__ __launch_bounds__(256)
void softmax_dropout(const float* __restrict__ S, u16* __restrict__ P) {
  const int tid  = threadIdx.x;
  const int lane = tid & 63;
  const int w    = tid >> 6;
  const int row  = blockIdx.x * 4 + w;   // one row per wave
  const float4* Sr = (const float4*)(S + (size_t)row * MROWS);
  float4 v[16];
#pragma unroll
  for (int i = 0; i < 16; ++i) v[i] = Sr[i * 64 + lane];
  float m = -3.0e38f;
#pragma unroll
  for (int i = 0; i < 16; ++i)
    m = fmaxf(m, fmaxf(fmaxf(v[i].x, v[i].y), fmaxf(v[i].z, v[i].w)));
#pragma unroll
  for (int off = 32; off > 0; off >>= 1) m = fmaxf(m, __shfl_xor(m, off, 64));
  float s = 0.0f;
#pragma unroll
  for (int i = 0; i < 16; ++i) {
    v[i].x = __expf(v[i].x - m); v[i].y = __expf(v[i].y - m);
    v[i].z = __expf(v[i].z - m); v[i].w = __expf(v[i].w - m);
    s += v[i].x + v[i].y + v[i].z + v[i].w;
  }
#pragma unroll
  for (int off = 32; off > 0; off >>= 1) s += __shfl_xor(s, off, 64);
  const float inv = 2.0f / s;            // softmax normalize * 1/(1-p)
  u16* Pr = P + (size_t)row * MROWS;
#pragma unroll
  for (int i = 0; i < 16; ++i) {
    int j0 = (i * 64 + lane) * 4;
    u32 base = (u32)row * 4096u + (u32)j0;
    float e[4] = {v[i].x, v[i].y, v[i].z, v[i].w};
    u16x4 o;
#pragma unroll
    for (int c = 0; c < 4; ++c) {
      u32 bits = threefry_bits(base + (u32)c);
      float val = (bits & 0x80000000u) ? 0.0f : e[c] * inv;   // uniform<0.5 == MSB 0
      o[c] = f2bf(val);
    }
    *(u16x4*)(Pr + j0) = o;
  }
}

// ============ split-K reduction of bf16 partials ============
__global__ __launch_bounds__(256)
void reduce4(const u16* __restrict__ p, float4* __restrict__ out) {
  size_t i = (size_t)blockIdx.x * 256 + threadIdx.x;   // float4 index
  const size_t NP = (size_t)MROWS * DDIM;
  u16x4 a = *(const u16x4*)(p + i*4);
  u16x4 b = *(const u16x4*)(p + NP + i*4);
  u16x4 c = *(const u16x4*)(p + 2*NP + i*4);
  u16x4 d = *(const u16x4*)(p + 3*NP + i*4);
  float4 r;
  r.x = bf2f(a[0]) + bf2f(b[0]) + bf2f(c[0]) + bf2f(d[0]);
  r.y = bf2f(a[1]) + bf2f(b[1]) + bf2f(c[1]) + bf2f(d[1]);
  r.z = bf2f(a[2]) + bf2f(b[2]) + bf2f(c[2]) + bf2f(d[2]);
  r.w = bf2f(a[3]) + bf2f(b[3]) + bf2f(c[3]) + bf2f(d[3]);
  out[i] = r;
}

// ============ launch ============
extern "C" void kernel_launch(void* const* d_in, const int* in_sizes, int n_in,
                              void* d_out, int out_size, void* d_ws, size_t ws_size,
                              hipStream_t stream) {
  const float* x1 = (const float*)d_in[0];
  const float* x2 = (const float*)d_in[1];
  float* out = (float*)d_out;
  char* ws = (char*)d_ws;

  // ws layout (bytes):
  //   XA [0,24M) | XB [24M,48M) | VT [48M,56M) | S [56M,120M)
  //   P (32M) overlays XA+XB after GEMM1 ; bf16 partials (32M) overlay S
  const size_t OFF_XB   = 25165824;
  const size_t OFF_VT   = 50331648;
  const size_t OFF_S    = 58720256;
  const size_t NEED     = 125829120;
  if (ws_size < NEED) {
    hipMemsetAsync(d_out, 0x7F, (size_t)out_size * sizeof(float), stream);
    return;
  }
  u16*   XA = (u16*)(ws);
  u16*   XB = (u16*)(ws + OFF_XB);
  u16*   VT = (u16*)(ws + OFF_VT);
  float* S  = (float*)(ws + OFF_S);
  u16*   PT = (u16*)(ws + OFF_S);       // bf16 partials reuse S region
  u16*   P  = (u16*)(ws);               // reuses XA(+XB) region

  expandA<<<2048, 256, 0, stream>>>((const float4*)x1, XA);
  castB_transpose<<<dim3(16, 64), 256, 0, stream>>>(x2, XB, VT);
  // S = (4*x1) @ x2^T via 3-term expanded K = 3072
  gemm_qk<<<dim3(16, 16, 1), 512, 0, stream>>>(XA, XB, S, 4096, 4096, 3072, 48);
  softmax_dropout<<<1024, 256, 0, stream>>>(S, P);
  // O = P @ V: split-K x4 (K=4096, 16 tiles/chunk), bf16 partials, then reduce
  gemm_pv<<<dim3(4, 16, 4), 512, 0, stream>>>(P, VT, PT, 4096, 1024, 4096, 16);
  reduce4<<<4096, 256, 0, stream>>>(PT, (float4*)out);
}